// Round 6
// baseline (617.388 us; speedup 1.0000x reference)
//
#include <hip/hip_runtime.h>
#include <math.h>

#define L_SEQ 192
#define B_SZ  4
#define H_D   768
#define N_LB  16

// ============================================================================
// G1: fused NT GEMMs (f32, 64x64 tile, 256 threads, reg double-buffer)
//   blocks [0,144)   : P[lb][o]  = h_share[lb][:]·Wn[o][0:768]
//                                + h_ner [lb][:]·Wn[o][768:1536]   (raw; bias+tanh in g2a)
//   blocks [144,432) : AC[lb][n] = h_ner[lb][:]·B[n][:],
//                      B[n][k] = n<768 ? W1[n][k] : W1[n-768][768+k]
//   (unchanged this round: no counters captured for it yet)
// ============================================================================
__global__ __launch_bounds__(256) void g1_gemm(
    const float* __restrict__ h_ner, const float* __restrict__ h_share,
    const float* __restrict__ Wn,
    const float* __restrict__ W1,
    float* __restrict__ P, float* __restrict__ AC)
{
    __shared__ float As[16][68];   // k-major, pad 68 -> conflict-free f4 reads
    __shared__ float Bs[16][68];

    const int tid = threadIdx.x;
    const int tx = tid & 15;          // n-dir micro index
    const int ty = tid >> 4;          // m-dir micro index
    const int sr = tid >> 2;          // staging row 0..63
    const int sc = (tid & 3) << 2;    // staging k-offset {0,4,8,12}

    const int bid = blockIdx.x;
    const bool isP = bid < 144;
    int tm, tn;
    if (isP) { tm = bid / 12; tn = bid - tm * 12; }
    else     { int t = bid - 144; tm = t / 24; tn = t - tm * 24; }
    const int m0 = tm * 64, n0 = tn * 64;

    int bro = 0, bco = 0;
    if (!isP) { if (n0 < 768) { bro = n0; bco = 0; } else { bro = n0 - 768; bco = 768; } }

    const int nsteps = isP ? 96 : 48;   // P: 2 virtual-K phases of 48
    float acc[4][4] = {};

    auto ldA = [&](int kt) -> float4 {
        const bool ph = isP && (kt >= 48);
        const int k0 = (kt - (ph ? 48 : 0)) << 4;
        const float* src = (isP && !ph) ? h_share : h_ner;
        return *(const float4*)&src[(m0 + sr) * H_D + k0 + sc];
    };
    auto ldB = [&](int kt) -> float4 {
        const bool ph = isP && (kt >= 48);
        const int k0 = (kt - (ph ? 48 : 0)) << 4;
        const float* p = isP ? &Wn[(n0 + sr) * 1536 + (ph ? 768 : 0) + k0 + sc]
                             : &W1[(bro + sr) * 2304 + bco + k0 + sc];
        return *(const float4*)p;
    };

    float4 av = ldA(0), bv = ldB(0);
    for (int kt = 0; kt < nsteps; ++kt) {
        __syncthreads();
        As[sc + 0][sr] = av.x; As[sc + 1][sr] = av.y; As[sc + 2][sr] = av.z; As[sc + 3][sr] = av.w;
        Bs[sc + 0][sr] = bv.x; Bs[sc + 1][sr] = bv.y; Bs[sc + 2][sr] = bv.z; Bs[sc + 3][sr] = bv.w;
        __syncthreads();
        if (kt + 1 < nsteps) { av = ldA(kt + 1); bv = ldB(kt + 1); }  // hide next-tile latency
        #pragma unroll
        for (int kk = 0; kk < 16; ++kk) {
            const float4 a4 = *(const float4*)&As[kk][ty << 2];
            const float4 b4 = *(const float4*)&Bs[kk][tx << 2];
            const float ar[4] = {a4.x, a4.y, a4.z, a4.w};
            const float bc[4] = {b4.x, b4.y, b4.z, b4.w};
            #pragma unroll
            for (int r = 0; r < 4; ++r)
                #pragma unroll
                for (int c = 0; c < 4; ++c)
                    acc[r][c] = fmaf(ar[r], bc[c], acc[r][c]);
        }
    }

    if (isP) {
        #pragma unroll
        for (int r = 0; r < 4; ++r) {
            const int m = m0 + (ty << 2) + r;
            float4 v = make_float4(acc[r][0], acc[r][1], acc[r][2], acc[r][3]);
            *(float4*)&P[m * 768 + n0 + (tx << 2)] = v;
        }
    } else {
        #pragma unroll
        for (int r = 0; r < 4; ++r) {
            const int m = m0 + (ty << 2) + r;
            float4 v = make_float4(acc[r][0], acc[r][1], acc[r][2], acc[r][3]);
            *(float4*)&AC[m * 1536 + n0 + (tx << 2)] = v;
        }
    }
}

// ============================================================================
// G2a: g[b][o] = tanh( bn[o] + max_l Praw[(l*4+b)*768 + o] )   (12 blocks x 256)
// ============================================================================
__global__ __launch_bounds__(256) void g2a_gmax(const float* __restrict__ P,
                                                const float* __restrict__ bn,
                                                float* __restrict__ g)
{
    const int idx = blockIdx.x * 256 + threadIdx.x;   // 0..3071 == b*768+o
    const int b = idx / 768;
    const int o = idx - b * 768;
    float m = -1e30f;
    for (int l = 0; l < L_SEQ; ++l)
        m = fmaxf(m, P[l * 3072 + b * 768 + o]);
    g[idx] = tanhf(bn[o] + m);
}

// ============================================================================
// G2b: dd[b][o] = sum_h g[b][h] * W1[o][1536+h] + b1[o]
// ============================================================================
__global__ __launch_bounds__(256) void g2b_dd(const float* __restrict__ g,
                                              const float* __restrict__ W1,
                                              const float* __restrict__ b1,
                                              float* __restrict__ dd)
{
    const int b = blockIdx.x & 3;
    const int og = blockIdx.x >> 2;          // 0..191
    const int w = threadIdx.x >> 6;
    const int lane = threadIdx.x & 63;
    const int o = og * 4 + w;
    const float* wr = W1 + o * 2304 + 1536;
    const float* gr = g + b * 768;
    float acc = 0.f;
    #pragma unroll
    for (int m = 0; m < 12; ++m) {
        const int h = lane + 64 * m;
        acc = fmaf(gr[h], wr[h], acc);
    }
    #pragma unroll
    for (int mm = 32; mm; mm >>= 1) acc += __shfl_xor(acc, mm, 64);
    if (lane == 0) dd[b * 768 + o] = acc + b1[o];
}

// ============================================================================
// EP v3: upper-triangle epilogue.
//   Grid 768 = 96 row-pairs x 4 b x 2 j-strides; 256 thr (4 waves).
//   LDS = 16 KB (rbuf only; Wt read from global -> L1/L2).
//     VGPR ~130 @ cap 170 (256,3) -> 3 blocks/CU, grid 768 = exactly 3/CU.
//   Label reduce: v1's proven per-wave LDS transpose (part[4][16] regs only;
//     v2's register butterfly spilled to scratch -> 1 GB HBM traffic).
//   Swizzle: col = t ^ ((row>>1)&15) -> bank = (row&1)*16 + col covers 32
//     banks over 64 lanes = exactly 2-way aliasing = free (m136).
// ============================================================================
__global__ __launch_bounds__(256, 3) void ep_kernel(
    const float* __restrict__ AC, const float* __restrict__ dd,
    const float* __restrict__ mask,
    const float* __restrict__ gamma, const float* __restrict__ beta,
    const float* __restrict__ Wt, const float* __restrict__ bt,
    float* __restrict__ out)
{
    __shared__ float rbuf[4][64][16];       // 16 KB total

    const int tid = threadIdx.x;
    const int b = blockIdx.x & 3;
    const int s = (blockIdx.x >> 2) & 1;
    const int x = blockIdx.x >> 3;          // 0..95
    const int w = tid >> 6;
    const int lane = tid & 63;
    const int jgrp = lane >> 4;             // which j of the tile this lane owns at the end
    const int tl = lane & 15;               // which label this lane owns at the end
    const int swz = (lane >> 1) & 15;       // write-side swizzle constant
    const float btv = bt[tl];
    const float4* wt4 = (const float4*)Wt;  // global; L1/L2-cached, off the LDS pipe

    #pragma unroll 1
    for (int half = 0; half < 2; ++half) {
        const int i = half ? (191 - x) : x;
        const float mi = mask[i * 4 + b];
        float4 pbase[3];
        {
            const float4* arow = (const float4*)&AC[(i * 4 + b) * 1536];
            #pragma unroll
            for (int k2 = 0; k2 < 3; ++k2) {
                const float4 a4 = arow[lane + (k2 << 6)];
                const float4 d4 = *(const float4*)&dd[b * 768 + (lane << 2) + (k2 << 8)];
                pbase[k2].x = a4.x + d4.x;
                pbase[k2].y = a4.y + d4.y;
                pbase[k2].z = a4.z + d4.z;
                pbase[k2].w = a4.w + d4.w;
            }
        }
        #pragma unroll 1
        for (int jt = i + (w << 2) + (s << 4); jt < L_SEQ; jt += 32) {
            float4 pre[4][3];
            float s1[4], s2[4];
            #pragma unroll
            for (int jj = 0; jj < 4; ++jj) {
                int j = jt + jj; if (j > 191) j = 191;   // clamped lanes masked at store
                const float4* crow = (const float4*)&AC[(j * 4 + b) * 1536 + 768];
                s1[jj] = 0.f; s2[jj] = 0.f;
                #pragma unroll
                for (int k2 = 0; k2 < 3; ++k2) {
                    const float4 cv = crow[lane + (k2 << 6)];
                    float4 p;
                    p.x = pbase[k2].x + cv.x;
                    p.y = pbase[k2].y + cv.y;
                    p.z = pbase[k2].z + cv.z;
                    p.w = pbase[k2].w + cv.w;
                    pre[jj][k2] = p;
                    s1[jj] += p.x + p.y + p.z + p.w;
                    s2[jj] = fmaf(p.x, p.x, fmaf(p.y, p.y, fmaf(p.z, p.z, fmaf(p.w, p.w, s2[jj]))));
                }
            }
            // 64-lane all-reduce of LN stats (8 values)
            #pragma unroll
            for (int m = 32; m; m >>= 1) {
                #pragma unroll
                for (int jj = 0; jj < 4; ++jj) {
                    s1[jj] += __shfl_xor(s1[jj], m, 64);
                    s2[jj] += __shfl_xor(s2[jj], m, 64);
                }
            }
            float mu[4], rs[4];
            #pragma unroll
            for (int jj = 0; jj < 4; ++jj) {
                mu[jj] = s1[jj] * (1.0f / 768.0f);
                const float var = s2[jj] * (1.0f / 768.0f) - mu[jj] * mu[jj];
                rs[jj] = 1.0f / sqrtf(var + 1e-5f);
            }
            // x = elu( LN(pre)*gamma + beta ); gamma/beta reloaded (L1-hot)
            #pragma unroll
            for (int k2 = 0; k2 < 3; ++k2) {
                const int ob = (lane << 2) + (k2 << 8);
                const float4 gm = *(const float4*)&gamma[ob];
                const float4 bt4 = *(const float4*)&beta[ob];
                #pragma unroll
                for (int jj = 0; jj < 4; ++jj) {
                    float4 p = pre[jj][k2];
                    p.x = (p.x - mu[jj]) * rs[jj] * gm.x + bt4.x;
                    p.y = (p.y - mu[jj]) * rs[jj] * gm.y + bt4.y;
                    p.z = (p.z - mu[jj]) * rs[jj] * gm.z + bt4.z;
                    p.w = (p.w - mu[jj]) * rs[jj] * gm.w + bt4.w;
                    p.x = p.x > 0.f ? p.x : __expf(p.x) - 1.f;
                    p.y = p.y > 0.f ? p.y : __expf(p.y) - 1.f;
                    p.z = p.z > 0.f ? p.z : __expf(p.z) - 1.f;
                    p.w = p.w > 0.f ? p.w : __expf(p.w) - 1.f;
                    pre[jj][k2] = p;
                }
            }
            // label partial dots: part[jj][t] over this lane's 12 h's
            float part[4][16];
            #pragma unroll
            for (int jj = 0; jj < 4; ++jj)
                #pragma unroll
                for (int t = 0; t < 16; ++t) part[jj][t] = 0.f;
            #pragma unroll
            for (int k2 = 0; k2 < 3; ++k2) {
                #pragma unroll
                for (int t = 0; t < 16; ++t) {
                    const float4 wv = wt4[t * 192 + lane + (k2 << 6)];
                    #pragma unroll
                    for (int jj = 0; jj < 4; ++jj) {
                        float acc = part[jj][t];
                        acc = fmaf(pre[jj][k2].x, wv.x, acc);
                        acc = fmaf(pre[jj][k2].y, wv.y, acc);
                        acc = fmaf(pre[jj][k2].z, wv.z, acc);
                        acc = fmaf(pre[jj][k2].w, wv.w, acc);
                        part[jj][t] = acc;
                    }
                }
            }
            // cross-lane reduce: per-wave LDS transpose, one jj per round.
            // write col = t ^ ((lane>>1)&15); read row r uses col = tl ^ ((r>>1)&15).
            float fin = 0.f;
            #pragma unroll
            for (int jj = 0; jj < 4; ++jj) {
                #pragma unroll
                for (int t = 0; t < 16; ++t)
                    rbuf[w][lane][t ^ swz] = part[jj][t];
                float acc = 0.f;
                #pragma unroll
                for (int s16 = 0; s16 < 16; ++s16) {
                    const int r = (jgrp << 4) + s16;
                    acc += rbuf[w][r][tl ^ ((r >> 1) & 15)];
                }
                acc += __shfl_xor(acc, 16, 64);
                acc += __shfl_xor(acc, 32, 64);
                if (jgrp == jj) fin = acc;
            }
            const int j = jt + jgrp;
            if (j < L_SEQ) {
                const float z = fin + btv;
                const float sg = 1.0f / (1.0f + __expf(-z));
                const float mj = mask[j * 4 + b];
                out[((i * L_SEQ + j) * 4 + b) * N_LB + tl] = sg * mi * mj;
            }
        }
    }
}

// ============================================================================
extern "C" void kernel_launch(void* const* d_in, const int* in_sizes, int n_in,
                              void* d_out, int out_size, void* d_ws, size_t ws_size,
                              hipStream_t stream)
{
    const float* h_ner   = (const float*)d_in[0];
    const float* h_share = (const float*)d_in[1];
    const float* mask    = (const float*)d_in[2];
    const float* Wn      = (const float*)d_in[3];
    const float* bn      = (const float*)d_in[4];
    const float* W1      = (const float*)d_in[5];
    const float* b1      = (const float*)d_in[6];
    const float* gamma   = (const float*)d_in[7];
    const float* beta    = (const float*)d_in[8];
    const float* Wt      = (const float*)d_in[9];
    const float* bt      = (const float*)d_in[10];

    float* P  = (float*)d_ws;            // 768*768
    float* AC = P + 768 * 768;           // 768*1536
    float* g  = AC + 768 * 1536;         // 4*768
    float* dd = g + 4 * 768;             // 4*768   (total ~6.8 MB)

    // zero output: lower triangle must be 0 (buffer is poisoned 0xAA)
    hipMemsetAsync(d_out, 0, (size_t)out_size * sizeof(float), stream);

    hipLaunchKernelGGL(g1_gemm, dim3(432), dim3(256), 0, stream,
                       h_ner, h_share, Wn, W1, P, AC);
    hipLaunchKernelGGL(g2a_gmax, dim3(12), dim3(256), 0, stream, P, bn, g);
    hipLaunchKernelGGL(g2b_dd, dim3(768), dim3(256), 0, stream, g, W1, b1, dd);
    hipLaunchKernelGGL(ep_kernel, dim3(768), dim3(256), 0, stream,
                       AC, dd, mask, gamma, beta, Wt, bt, (float*)d_out);
}

// Round 11
// 330.415 us; speedup vs baseline: 1.8685x; 1.8685x over previous
//
#include <hip/hip_runtime.h>
#include <math.h>

#define L_SEQ 192
#define B_SZ  4
#define H_D   768
#define N_LB  16

// ============================================================================
// G1: fused NT GEMMs (f32, 64x64 tile, 256 threads, reg double-buffer)
//   blocks [0,144)   : P[lb][o]  = h_share[lb][:]·Wn[o][0:768]
//                                + h_ner [lb][:]·Wn[o][768:1536]   (raw; bias+tanh in g2a)
//   blocks [144,432) : AC[lb][n] = h_ner[lb][:]·B[n][:],
//                      B[n][k] = n<768 ? W1[n][k] : W1[n-768][768+k]
// ============================================================================
__global__ __launch_bounds__(256) void g1_gemm(
    const float* __restrict__ h_ner, const float* __restrict__ h_share,
    const float* __restrict__ Wn,
    const float* __restrict__ W1,
    float* __restrict__ P, float* __restrict__ AC)
{
    __shared__ float As[16][68];   // k-major, pad 68 -> conflict-free f4 reads
    __shared__ float Bs[16][68];

    const int tid = threadIdx.x;
    const int tx = tid & 15;          // n-dir micro index
    const int ty = tid >> 4;          // m-dir micro index
    const int sr = tid >> 2;          // staging row 0..63
    const int sc = (tid & 3) << 2;    // staging k-offset {0,4,8,12}

    const int bid = blockIdx.x;
    const bool isP = bid < 144;
    int tm, tn;
    if (isP) { tm = bid / 12; tn = bid - tm * 12; }
    else     { int t = bid - 144; tm = t / 24; tn = t - tm * 24; }
    const int m0 = tm * 64, n0 = tn * 64;

    int bro = 0, bco = 0;
    if (!isP) { if (n0 < 768) { bro = n0; bco = 0; } else { bro = n0 - 768; bco = 768; } }

    const int nsteps = isP ? 96 : 48;   // P: 2 virtual-K phases of 48
    float acc[4][4] = {};

    auto ldA = [&](int kt) -> float4 {
        const bool ph = isP && (kt >= 48);
        const int k0 = (kt - (ph ? 48 : 0)) << 4;
        const float* src = (isP && !ph) ? h_share : h_ner;
        return *(const float4*)&src[(m0 + sr) * H_D + k0 + sc];
    };
    auto ldB = [&](int kt) -> float4 {
        const bool ph = isP && (kt >= 48);
        const int k0 = (kt - (ph ? 48 : 0)) << 4;
        const float* p = isP ? &Wn[(n0 + sr) * 1536 + (ph ? 768 : 0) + k0 + sc]
                             : &W1[(bro + sr) * 2304 + bco + k0 + sc];
        return *(const float4*)p;
    };

    float4 av = ldA(0), bv = ldB(0);
    for (int kt = 0; kt < nsteps; ++kt) {
        __syncthreads();
        As[sc + 0][sr] = av.x; As[sc + 1][sr] = av.y; As[sc + 2][sr] = av.z; As[sc + 3][sr] = av.w;
        Bs[sc + 0][sr] = bv.x; Bs[sc + 1][sr] = bv.y; Bs[sc + 2][sr] = bv.z; Bs[sc + 3][sr] = bv.w;
        __syncthreads();
        if (kt + 1 < nsteps) { av = ldA(kt + 1); bv = ldB(kt + 1); }  // hide next-tile latency
        #pragma unroll
        for (int kk = 0; kk < 16; ++kk) {
            const float4 a4 = *(const float4*)&As[kk][ty << 2];
            const float4 b4 = *(const float4*)&Bs[kk][tx << 2];
            const float ar[4] = {a4.x, a4.y, a4.z, a4.w};
            const float bc[4] = {b4.x, b4.y, b4.z, b4.w};
            #pragma unroll
            for (int r = 0; r < 4; ++r)
                #pragma unroll
                for (int c = 0; c < 4; ++c)
                    acc[r][c] = fmaf(ar[r], bc[c], acc[r][c]);
        }
    }

    if (isP) {
        #pragma unroll
        for (int r = 0; r < 4; ++r) {
            const int m = m0 + (ty << 2) + r;
            float4 v = make_float4(acc[r][0], acc[r][1], acc[r][2], acc[r][3]);
            *(float4*)&P[m * 768 + n0 + (tx << 2)] = v;
        }
    } else {
        #pragma unroll
        for (int r = 0; r < 4; ++r) {
            const int m = m0 + (ty << 2) + r;
            float4 v = make_float4(acc[r][0], acc[r][1], acc[r][2], acc[r][3]);
            *(float4*)&AC[m * 1536 + n0 + (tx << 2)] = v;
        }
    }
}

// ============================================================================
// G2a: g[b][o] = tanh( bn[o] + max_l Praw[(l*4+b)*768 + o] )   (12 blocks x 256)
// ============================================================================
__global__ __launch_bounds__(256) void g2a_gmax(const float* __restrict__ P,
                                                const float* __restrict__ bn,
                                                float* __restrict__ g)
{
    const int idx = blockIdx.x * 256 + threadIdx.x;   // 0..3071 == b*768+o
    const int b = idx / 768;
    const int o = idx - b * 768;
    float m = -1e30f;
    for (int l = 0; l < L_SEQ; ++l)
        m = fmaxf(m, P[l * 3072 + b * 768 + o]);
    g[idx] = tanhf(bn[o] + m);
}

// ============================================================================
// G2b: dd[b][o] = sum_h g[b][h] * W1[o][1536+h] + b1[o]
// ============================================================================
__global__ __launch_bounds__(256) void g2b_dd(const float* __restrict__ g,
                                              const float* __restrict__ W1,
                                              const float* __restrict__ b1,
                                              float* __restrict__ dd)
{
    const int b = blockIdx.x & 3;
    const int og = blockIdx.x >> 2;          // 0..191
    const int w = threadIdx.x >> 6;
    const int lane = threadIdx.x & 63;
    const int o = og * 4 + w;
    const float* wr = W1 + o * 2304 + 1536;
    const float* gr = g + b * 768;
    float acc = 0.f;
    #pragma unroll
    for (int m = 0; m < 12; ++m) {
        const int h = lane + 64 * m;
        acc = fmaf(gr[h], wr[h], acc);
    }
    #pragma unroll
    for (int mm = 32; mm; mm >>= 1) acc += __shfl_xor(acc, mm, 64);
    if (lane == 0) dd[b * 768 + o] = acc + b1[o];
}

// ============================================================================
// EP v4 == v3 minus the launch-bounds min-waves clause.
//   (256,3) forced the allocator under the 128-VGPR occupancy step (gfx950
//   wave slots step at VGPR 64/128/256 — no 3-wave step exists), spilling
//   part[4][16] to scratch: 1.26 GB HBM traffic, 84 VGPR, 424 us.
//   Unconstrained (like round-3 v1, 120 VGPR, no spill): ~4 waves/SIMD by
//   VGPR, 16 KB LDS permits it, grid 768 = 3 blocks/CU fully resident.
// ============================================================================
__global__ __launch_bounds__(256) void ep_kernel(
    const float* __restrict__ AC, const float* __restrict__ dd,
    const float* __restrict__ mask,
    const float* __restrict__ gamma, const float* __restrict__ beta,
    const float* __restrict__ Wt, const float* __restrict__ bt,
    float* __restrict__ out)
{
    __shared__ float rbuf[4][64][16];       // 16 KB total

    const int tid = threadIdx.x;
    const int b = blockIdx.x & 3;
    const int s = (blockIdx.x >> 2) & 1;
    const int x = blockIdx.x >> 3;          // 0..95
    const int w = tid >> 6;
    const int lane = tid & 63;
    const int jgrp = lane >> 4;             // which j of the tile this lane owns at the end
    const int tl = lane & 15;               // which label this lane owns at the end
    const int swz = (lane >> 1) & 15;       // write-side swizzle constant
    const float btv = bt[tl];
    const float4* wt4 = (const float4*)Wt;  // global; L1/L2-cached, off the LDS pipe

    #pragma unroll 1
    for (int half = 0; half < 2; ++half) {
        const int i = half ? (191 - x) : x;
        const float mi = mask[i * 4 + b];
        float4 pbase[3];
        {
            const float4* arow = (const float4*)&AC[(i * 4 + b) * 1536];
            #pragma unroll
            for (int k2 = 0; k2 < 3; ++k2) {
                const float4 a4 = arow[lane + (k2 << 6)];
                const float4 d4 = *(const float4*)&dd[b * 768 + (lane << 2) + (k2 << 8)];
                pbase[k2].x = a4.x + d4.x;
                pbase[k2].y = a4.y + d4.y;
                pbase[k2].z = a4.z + d4.z;
                pbase[k2].w = a4.w + d4.w;
            }
        }
        #pragma unroll 1
        for (int jt = i + (w << 2) + (s << 4); jt < L_SEQ; jt += 32) {
            float4 pre[4][3];
            float s1[4], s2[4];
            #pragma unroll
            for (int jj = 0; jj < 4; ++jj) {
                int j = jt + jj; if (j > 191) j = 191;   // clamped lanes masked at store
                const float4* crow = (const float4*)&AC[(j * 4 + b) * 1536 + 768];
                s1[jj] = 0.f; s2[jj] = 0.f;
                #pragma unroll
                for (int k2 = 0; k2 < 3; ++k2) {
                    const float4 cv = crow[lane + (k2 << 6)];
                    float4 p;
                    p.x = pbase[k2].x + cv.x;
                    p.y = pbase[k2].y + cv.y;
                    p.z = pbase[k2].z + cv.z;
                    p.w = pbase[k2].w + cv.w;
                    pre[jj][k2] = p;
                    s1[jj] += p.x + p.y + p.z + p.w;
                    s2[jj] = fmaf(p.x, p.x, fmaf(p.y, p.y, fmaf(p.z, p.z, fmaf(p.w, p.w, s2[jj]))));
                }
            }
            // 64-lane all-reduce of LN stats (8 values)
            #pragma unroll
            for (int m = 32; m; m >>= 1) {
                #pragma unroll
                for (int jj = 0; jj < 4; ++jj) {
                    s1[jj] += __shfl_xor(s1[jj], m, 64);
                    s2[jj] += __shfl_xor(s2[jj], m, 64);
                }
            }
            float mu[4], rs[4];
            #pragma unroll
            for (int jj = 0; jj < 4; ++jj) {
                mu[jj] = s1[jj] * (1.0f / 768.0f);
                const float var = s2[jj] * (1.0f / 768.0f) - mu[jj] * mu[jj];
                rs[jj] = 1.0f / sqrtf(var + 1e-5f);
            }
            // x = elu( LN(pre)*gamma + beta ); gamma/beta reloaded (L1-hot)
            #pragma unroll
            for (int k2 = 0; k2 < 3; ++k2) {
                const int ob = (lane << 2) + (k2 << 8);
                const float4 gm = *(const float4*)&gamma[ob];
                const float4 bt4 = *(const float4*)&beta[ob];
                #pragma unroll
                for (int jj = 0; jj < 4; ++jj) {
                    float4 p = pre[jj][k2];
                    p.x = (p.x - mu[jj]) * rs[jj] * gm.x + bt4.x;
                    p.y = (p.y - mu[jj]) * rs[jj] * gm.y + bt4.y;
                    p.z = (p.z - mu[jj]) * rs[jj] * gm.z + bt4.z;
                    p.w = (p.w - mu[jj]) * rs[jj] * gm.w + bt4.w;
                    p.x = p.x > 0.f ? p.x : __expf(p.x) - 1.f;
                    p.y = p.y > 0.f ? p.y : __expf(p.y) - 1.f;
                    p.z = p.z > 0.f ? p.z : __expf(p.z) - 1.f;
                    p.w = p.w > 0.f ? p.w : __expf(p.w) - 1.f;
                    pre[jj][k2] = p;
                }
            }
            // label partial dots: part[jj][t] over this lane's 12 h's
            float part[4][16];
            #pragma unroll
            for (int jj = 0; jj < 4; ++jj)
                #pragma unroll
                for (int t = 0; t < 16; ++t) part[jj][t] = 0.f;
            #pragma unroll
            for (int k2 = 0; k2 < 3; ++k2) {
                #pragma unroll
                for (int t = 0; t < 16; ++t) {
                    const float4 wv = wt4[t * 192 + lane + (k2 << 6)];
                    #pragma unroll
                    for (int jj = 0; jj < 4; ++jj) {
                        float acc = part[jj][t];
                        acc = fmaf(pre[jj][k2].x, wv.x, acc);
                        acc = fmaf(pre[jj][k2].y, wv.y, acc);
                        acc = fmaf(pre[jj][k2].z, wv.z, acc);
                        acc = fmaf(pre[jj][k2].w, wv.w, acc);
                        part[jj][t] = acc;
                    }
                }
            }
            // cross-lane reduce: per-wave LDS transpose, one jj per round.
            // write col = t ^ ((lane>>1)&15); read row r uses col = tl ^ ((r>>1)&15).
            float fin = 0.f;
            #pragma unroll
            for (int jj = 0; jj < 4; ++jj) {
                #pragma unroll
                for (int t = 0; t < 16; ++t)
                    rbuf[w][lane][t ^ swz] = part[jj][t];
                float acc = 0.f;
                #pragma unroll
                for (int s16 = 0; s16 < 16; ++s16) {
                    const int r = (jgrp << 4) + s16;
                    acc += rbuf[w][r][tl ^ ((r >> 1) & 15)];
                }
                acc += __shfl_xor(acc, 16, 64);
                acc += __shfl_xor(acc, 32, 64);
                if (jgrp == jj) fin = acc;
            }
            const int j = jt + jgrp;
            if (j < L_SEQ) {
                const float z = fin + btv;
                const float sg = 1.0f / (1.0f + __expf(-z));
                const float mj = mask[j * 4 + b];
                out[((i * L_SEQ + j) * 4 + b) * N_LB + tl] = sg * mi * mj;
            }
        }
    }
}

// ============================================================================
extern "C" void kernel_launch(void* const* d_in, const int* in_sizes, int n_in,
                              void* d_out, int out_size, void* d_ws, size_t ws_size,
                              hipStream_t stream)
{
    const float* h_ner   = (const float*)d_in[0];
    const float* h_share = (const float*)d_in[1];
    const float* mask    = (const float*)d_in[2];
    const float* Wn      = (const float*)d_in[3];
    const float* bn      = (const float*)d_in[4];
    const float* W1      = (const float*)d_in[5];
    const float* b1      = (const float*)d_in[6];
    const float* gamma   = (const float*)d_in[7];
    const float* beta    = (const float*)d_in[8];
    const float* Wt      = (const float*)d_in[9];
    const float* bt      = (const float*)d_in[10];

    float* P  = (float*)d_ws;            // 768*768
    float* AC = P + 768 * 768;           // 768*1536
    float* g  = AC + 768 * 1536;         // 4*768
    float* dd = g + 4 * 768;             // 4*768   (total ~6.8 MB)

    // zero output: lower triangle must be 0 (buffer is poisoned 0xAA)
    hipMemsetAsync(d_out, 0, (size_t)out_size * sizeof(float), stream);

    hipLaunchKernelGGL(g1_gemm, dim3(432), dim3(256), 0, stream,
                       h_ner, h_share, Wn, W1, P, AC);
    hipLaunchKernelGGL(g2a_gmax, dim3(12), dim3(256), 0, stream, P, bn, g);
    hipLaunchKernelGGL(g2b_dd, dim3(768), dim3(256), 0, stream, g, W1, b1, dd);
    hipLaunchKernelGGL(ep_kernel, dim3(768), dim3(256), 0, stream,
                       AC, dd, mask, gamma, beta, Wt, bt, (float*)d_out);
}

// Round 12
// 273.088 us; speedup vs baseline: 2.2608x; 1.2099x over previous
//
#include <hip/hip_runtime.h>
#include <math.h>

#define L_SEQ 192
#define B_SZ  4
#define H_D   768
#define N_LB  16

// ============================================================================
// G1: fused NT GEMMs (f32, 64x64 tile, 256 threads, reg double-buffer)
//   blocks [0,144)   : P[lb][o]  = h_share[lb][:]·Wn[o][0:768]
//                                + h_ner [lb][:]·Wn[o][768:1536]   (raw; bias+tanh in g2a)
//   blocks [144,432) : AC[lb][n] = h_ner[lb][:]·B[n][:],
//                      B[n][k] = n<768 ? W1[n][k] : W1[n-768][768+k]
// ============================================================================
__global__ __launch_bounds__(256) void g1_gemm(
    const float* __restrict__ h_ner, const float* __restrict__ h_share,
    const float* __restrict__ Wn,
    const float* __restrict__ W1,
    float* __restrict__ P, float* __restrict__ AC)
{
    __shared__ float As[16][68];   // k-major, pad 68 -> conflict-free f4 reads
    __shared__ float Bs[16][68];

    const int tid = threadIdx.x;
    const int tx = tid & 15;          // n-dir micro index
    const int ty = tid >> 4;          // m-dir micro index
    const int sr = tid >> 2;          // staging row 0..63
    const int sc = (tid & 3) << 2;    // staging k-offset {0,4,8,12}

    const int bid = blockIdx.x;
    const bool isP = bid < 144;
    int tm, tn;
    if (isP) { tm = bid / 12; tn = bid - tm * 12; }
    else     { int t = bid - 144; tm = t / 24; tn = t - tm * 24; }
    const int m0 = tm * 64, n0 = tn * 64;

    int bro = 0, bco = 0;
    if (!isP) { if (n0 < 768) { bro = n0; bco = 0; } else { bro = n0 - 768; bco = 768; } }

    const int nsteps = isP ? 96 : 48;   // P: 2 virtual-K phases of 48
    float acc[4][4] = {};

    auto ldA = [&](int kt) -> float4 {
        const bool ph = isP && (kt >= 48);
        const int k0 = (kt - (ph ? 48 : 0)) << 4;
        const float* src = (isP && !ph) ? h_share : h_ner;
        return *(const float4*)&src[(m0 + sr) * H_D + k0 + sc];
    };
    auto ldB = [&](int kt) -> float4 {
        const bool ph = isP && (kt >= 48);
        const int k0 = (kt - (ph ? 48 : 0)) << 4;
        const float* p = isP ? &Wn[(n0 + sr) * 1536 + (ph ? 768 : 0) + k0 + sc]
                             : &W1[(bro + sr) * 2304 + bco + k0 + sc];
        return *(const float4*)p;
    };

    float4 av = ldA(0), bv = ldB(0);
    for (int kt = 0; kt < nsteps; ++kt) {
        __syncthreads();
        As[sc + 0][sr] = av.x; As[sc + 1][sr] = av.y; As[sc + 2][sr] = av.z; As[sc + 3][sr] = av.w;
        Bs[sc + 0][sr] = bv.x; Bs[sc + 1][sr] = bv.y; Bs[sc + 2][sr] = bv.z; Bs[sc + 3][sr] = bv.w;
        __syncthreads();
        if (kt + 1 < nsteps) { av = ldA(kt + 1); bv = ldB(kt + 1); }  // hide next-tile latency
        #pragma unroll
        for (int kk = 0; kk < 16; ++kk) {
            const float4 a4 = *(const float4*)&As[kk][ty << 2];
            const float4 b4 = *(const float4*)&Bs[kk][tx << 2];
            const float ar[4] = {a4.x, a4.y, a4.z, a4.w};
            const float bc[4] = {b4.x, b4.y, b4.z, b4.w};
            #pragma unroll
            for (int r = 0; r < 4; ++r)
                #pragma unroll
                for (int c = 0; c < 4; ++c)
                    acc[r][c] = fmaf(ar[r], bc[c], acc[r][c]);
        }
    }

    if (isP) {
        #pragma unroll
        for (int r = 0; r < 4; ++r) {
            const int m = m0 + (ty << 2) + r;
            float4 v = make_float4(acc[r][0], acc[r][1], acc[r][2], acc[r][3]);
            *(float4*)&P[m * 768 + n0 + (tx << 2)] = v;
        }
    } else {
        #pragma unroll
        for (int r = 0; r < 4; ++r) {
            const int m = m0 + (ty << 2) + r;
            float4 v = make_float4(acc[r][0], acc[r][1], acc[r][2], acc[r][3]);
            *(float4*)&AC[m * 1536 + n0 + (tx << 2)] = v;
        }
    }
}

// ============================================================================
// G2a: g[b][o] = tanh( bn[o] + max_l Praw[(l*4+b)*768 + o] )   (12 blocks x 256)
// ============================================================================
__global__ __launch_bounds__(256) void g2a_gmax(const float* __restrict__ P,
                                                const float* __restrict__ bn,
                                                float* __restrict__ g)
{
    const int idx = blockIdx.x * 256 + threadIdx.x;   // 0..3071 == b*768+o
    const int b = idx / 768;
    const int o = idx - b * 768;
    float m = -1e30f;
    for (int l = 0; l < L_SEQ; ++l)
        m = fmaxf(m, P[l * 3072 + b * 768 + o]);
    g[idx] = tanhf(bn[o] + m);
}

// ============================================================================
// G2b: dd[b][o] = sum_h g[b][h] * W1[o][1536+h] + b1[o]
// ============================================================================
__global__ __launch_bounds__(256) void g2b_dd(const float* __restrict__ g,
                                              const float* __restrict__ W1,
                                              const float* __restrict__ b1,
                                              float* __restrict__ dd)
{
    const int b = blockIdx.x & 3;
    const int og = blockIdx.x >> 2;          // 0..191
    const int w = threadIdx.x >> 6;
    const int lane = threadIdx.x & 63;
    const int o = og * 4 + w;
    const float* wr = W1 + o * 2304 + 1536;
    const float* gr = g + b * 768;
    float acc = 0.f;
    #pragma unroll
    for (int m = 0; m < 12; ++m) {
        const int h = lane + 64 * m;
        acc = fmaf(gr[h], wr[h], acc);
    }
    #pragma unroll
    for (int mm = 32; mm; mm >>= 1) acc += __shfl_xor(acc, mm, 64);
    if (lane == 0) dd[b * 768 + o] = acc + b1[o];
}

// ============================================================================
// EP v5 = v4 + Wt staged in LDS (the one variable changed this round).
//   Round-11 evidence: Wt-from-global made the scheduler prefetch ~96 VMEM
//   loads/tile and inflate to 256 VGPR (2 waves/SIMD, 10% occupancy, 152 us).
//   Round-3 v1 (same part/pre structure, Wt in LDS, plain bounds) = 120 VGPR.
//   ds_read latency needs no deep prefetch -> allocator stays ~120.
//   LDS = 48 KB wt_s + 16 KB rbuf = 64 KB -> 2 blocks/CU; grid 768 keeps both
//   slots fed (v1's 115 us ran at ~1.5 blocks/CU with 2x the bank conflicts).
// ============================================================================
__global__ __launch_bounds__(256) void ep_kernel(
    const float* __restrict__ AC, const float* __restrict__ dd,
    const float* __restrict__ mask,
    const float* __restrict__ gamma, const float* __restrict__ beta,
    const float* __restrict__ Wt, const float* __restrict__ bt,
    float* __restrict__ out)
{
    __shared__ float wt_s[N_LB * H_D];      // 48 KB
    __shared__ float rbuf[4][64][16];       // 16 KB  (total 64 KB)

    const int tid = threadIdx.x;
    {   // stage Wt as float4 (12 per thread)
        const float4* src = (const float4*)Wt;
        float4* dst = (float4*)wt_s;
        #pragma unroll
        for (int r = 0; r < 12; ++r) dst[tid + (r << 8)] = src[tid + (r << 8)];
    }

    const int b = blockIdx.x & 3;
    const int s = (blockIdx.x >> 2) & 1;
    const int x = blockIdx.x >> 3;          // 0..95
    const int w = tid >> 6;
    const int lane = tid & 63;
    const int jgrp = lane >> 4;             // which j of the tile this lane owns at the end
    const int tl = lane & 15;               // which label this lane owns at the end
    const int swz = (lane >> 1) & 15;       // write-side swizzle constant
    const float btv = bt[tl];
    const float4* wt4 = (const float4*)wt_s;

    __syncthreads();

    #pragma unroll 1
    for (int half = 0; half < 2; ++half) {
        const int i = half ? (191 - x) : x;
        const float mi = mask[i * 4 + b];
        float4 pbase[3];
        {
            const float4* arow = (const float4*)&AC[(i * 4 + b) * 1536];
            #pragma unroll
            for (int k2 = 0; k2 < 3; ++k2) {
                const float4 a4 = arow[lane + (k2 << 6)];
                const float4 d4 = *(const float4*)&dd[b * 768 + (lane << 2) + (k2 << 8)];
                pbase[k2].x = a4.x + d4.x;
                pbase[k2].y = a4.y + d4.y;
                pbase[k2].z = a4.z + d4.z;
                pbase[k2].w = a4.w + d4.w;
            }
        }
        #pragma unroll 1
        for (int jt = i + (w << 2) + (s << 4); jt < L_SEQ; jt += 32) {
            float4 pre[4][3];
            float s1[4], s2[4];
            #pragma unroll
            for (int jj = 0; jj < 4; ++jj) {
                int j = jt + jj; if (j > 191) j = 191;   // clamped lanes masked at store
                const float4* crow = (const float4*)&AC[(j * 4 + b) * 1536 + 768];
                s1[jj] = 0.f; s2[jj] = 0.f;
                #pragma unroll
                for (int k2 = 0; k2 < 3; ++k2) {
                    const float4 cv = crow[lane + (k2 << 6)];
                    float4 p;
                    p.x = pbase[k2].x + cv.x;
                    p.y = pbase[k2].y + cv.y;
                    p.z = pbase[k2].z + cv.z;
                    p.w = pbase[k2].w + cv.w;
                    pre[jj][k2] = p;
                    s1[jj] += p.x + p.y + p.z + p.w;
                    s2[jj] = fmaf(p.x, p.x, fmaf(p.y, p.y, fmaf(p.z, p.z, fmaf(p.w, p.w, s2[jj]))));
                }
            }
            // 64-lane all-reduce of LN stats (8 values)
            #pragma unroll
            for (int m = 32; m; m >>= 1) {
                #pragma unroll
                for (int jj = 0; jj < 4; ++jj) {
                    s1[jj] += __shfl_xor(s1[jj], m, 64);
                    s2[jj] += __shfl_xor(s2[jj], m, 64);
                }
            }
            float mu[4], rs[4];
            #pragma unroll
            for (int jj = 0; jj < 4; ++jj) {
                mu[jj] = s1[jj] * (1.0f / 768.0f);
                const float var = s2[jj] * (1.0f / 768.0f) - mu[jj] * mu[jj];
                rs[jj] = 1.0f / sqrtf(var + 1e-5f);
            }
            // x = elu( LN(pre)*gamma + beta ); gamma/beta reloaded (L1-hot)
            #pragma unroll
            for (int k2 = 0; k2 < 3; ++k2) {
                const int ob = (lane << 2) + (k2 << 8);
                const float4 gm = *(const float4*)&gamma[ob];
                const float4 bt4 = *(const float4*)&beta[ob];
                #pragma unroll
                for (int jj = 0; jj < 4; ++jj) {
                    float4 p = pre[jj][k2];
                    p.x = (p.x - mu[jj]) * rs[jj] * gm.x + bt4.x;
                    p.y = (p.y - mu[jj]) * rs[jj] * gm.y + bt4.y;
                    p.z = (p.z - mu[jj]) * rs[jj] * gm.z + bt4.z;
                    p.w = (p.w - mu[jj]) * rs[jj] * gm.w + bt4.w;
                    p.x = p.x > 0.f ? p.x : __expf(p.x) - 1.f;
                    p.y = p.y > 0.f ? p.y : __expf(p.y) - 1.f;
                    p.z = p.z > 0.f ? p.z : __expf(p.z) - 1.f;
                    p.w = p.w > 0.f ? p.w : __expf(p.w) - 1.f;
                    pre[jj][k2] = p;
                }
            }
            // label partial dots: part[jj][t] over this lane's 12 h's (wt from LDS)
            float part[4][16];
            #pragma unroll
            for (int jj = 0; jj < 4; ++jj)
                #pragma unroll
                for (int t = 0; t < 16; ++t) part[jj][t] = 0.f;
            #pragma unroll
            for (int k2 = 0; k2 < 3; ++k2) {
                #pragma unroll
                for (int t = 0; t < 16; ++t) {
                    const float4 wv = wt4[t * 192 + lane + (k2 << 6)];
                    #pragma unroll
                    for (int jj = 0; jj < 4; ++jj) {
                        float acc = part[jj][t];
                        acc = fmaf(pre[jj][k2].x, wv.x, acc);
                        acc = fmaf(pre[jj][k2].y, wv.y, acc);
                        acc = fmaf(pre[jj][k2].z, wv.z, acc);
                        acc = fmaf(pre[jj][k2].w, wv.w, acc);
                        part[jj][t] = acc;
                    }
                }
            }
            // cross-lane reduce: per-wave LDS transpose, one jj per round.
            // write col = t ^ ((lane>>1)&15); read row r uses col = tl ^ ((r>>1)&15).
            float fin = 0.f;
            #pragma unroll
            for (int jj = 0; jj < 4; ++jj) {
                #pragma unroll
                for (int t = 0; t < 16; ++t)
                    rbuf[w][lane][t ^ swz] = part[jj][t];
                float acc = 0.f;
                #pragma unroll
                for (int s16 = 0; s16 < 16; ++s16) {
                    const int r = (jgrp << 4) + s16;
                    acc += rbuf[w][r][tl ^ ((r >> 1) & 15)];
                }
                acc += __shfl_xor(acc, 16, 64);
                acc += __shfl_xor(acc, 32, 64);
                if (jgrp == jj) fin = acc;
            }
            const int j = jt + jgrp;
            if (j < L_SEQ) {
                const float z = fin + btv;
                const float sg = 1.0f / (1.0f + __expf(-z));
                const float mj = mask[j * 4 + b];
                out[((i * L_SEQ + j) * 4 + b) * N_LB + tl] = sg * mi * mj;
            }
        }
    }
}

// ============================================================================
extern "C" void kernel_launch(void* const* d_in, const int* in_sizes, int n_in,
                              void* d_out, int out_size, void* d_ws, size_t ws_size,
                              hipStream_t stream)
{
    const float* h_ner   = (const float*)d_in[0];
    const float* h_share = (const float*)d_in[1];
    const float* mask    = (const float*)d_in[2];
    const float* Wn      = (const float*)d_in[3];
    const float* bn      = (const float*)d_in[4];
    const float* W1      = (const float*)d_in[5];
    const float* b1      = (const float*)d_in[6];
    const float* gamma   = (const float*)d_in[7];
    const float* beta    = (const float*)d_in[8];
    const float* Wt      = (const float*)d_in[9];
    const float* bt      = (const float*)d_in[10];

    float* P  = (float*)d_ws;            // 768*768
    float* AC = P + 768 * 768;           // 768*1536
    float* g  = AC + 768 * 1536;         // 4*768
    float* dd = g + 4 * 768;             // 4*768   (total ~6.8 MB)

    // zero output: lower triangle must be 0 (buffer is poisoned 0xAA)
    hipMemsetAsync(d_out, 0, (size_t)out_size * sizeof(float), stream);

    hipLaunchKernelGGL(g1_gemm, dim3(432), dim3(256), 0, stream,
                       h_ner, h_share, Wn, W1, P, AC);
    hipLaunchKernelGGL(g2a_gmax, dim3(12), dim3(256), 0, stream, P, bn, g);
    hipLaunchKernelGGL(g2b_dd, dim3(768), dim3(256), 0, stream, g, W1, b1, dd);
    hipLaunchKernelGGL(ep_kernel, dim3(768), dim3(256), 0, stream,
                       AC, dd, mask, gamma, beta, Wt, bt, (float*)d_out);
}